// Round 6
// baseline (48.704 us; speedup 1.0000x reference)
//
#include <hip/hip_runtime.h>

typedef __bf16 bf16x8 __attribute__((ext_vector_type(8)));
typedef float  f32x16 __attribute__((ext_vector_type(16)));

#define NI 256
#define NT 256
#define NL 32
#define NE 128
#define HW 49
#define NEG_INF (-3.0e38f)

// Block: 4 waves = 2 images x 2 m-halves. Grid: 1024 = 128 pairs x 8 chunks
// (32 texts) -> 4 blocks/CU (16 waves/CU), all co-resident, zero tail.
// LDS 40KB: 2 x 16KB text double-buffer (XOR-swizzled) + 8KB colmax.
// Per text/wave: 8 ds_read_b128 + 8 MFMA + fmax tree + 1 ds_max.
// blockIdx%8 = text-chunk -> all readers of a chunk on one XCD (L2-resident).
__global__ __launch_bounds__(256, 4)
void clip_match_kernel(const float* __restrict__ img,
                       const float* __restrict__ txt,
                       const int* __restrict__ tlen,
                       const float* __restrict__ nlt,
                       float* __restrict__ out)
{
    const int tid  = threadIdx.x;
    const int wave = tid >> 6, lane = tid & 63;
    const int ml   = lane & 31, h = lane >> 5;
    const int tb   = blockIdx.x & 7;     // text chunk (32 texts)
    const int ip   = blockIdx.x >> 3;    // image pair 0..127
    const int ii   = wave & 1;           // image within pair
    const int mh   = wave >> 1;          // m-half (rows mh*32..mh*32+31)
    const int img_i = ip * 2 + ii;

    const float scale = expf(nlt[0]);

    __shared__ __align__(16) __bf16 buf[2][2 * NL * NE];  // 2 x 16 KB (2 texts)
    __shared__ __align__(16) float  colmax[2][NL][32];    // [img][text][col] 8KB

    // ---- init colmax to -inf (2048 floats, 8 per thread) ----
    {
        float4 ninf4 = make_float4(NEG_INF, NEG_INF, NEG_INF, NEG_INF);
        float* base = &colmax[0][0][0];
        *(float4*)(base + tid * 8)     = ninf4;
        *(float4*)(base + tid * 8 + 4) = ninf4;
    }

    // ---- A fragments: rows mh*32+ml of image img_i, 32 VGPRs ----
    // lane holds A[m = mh*32+ml, k = ks*16 + h*8 + j]; A[m,k] = img[i,e=k,hw=m]
    bf16x8 afrag[8];
    {
        int m = mh * 32 + ml;
        if (m > HW - 1) m = HW - 1;          // clamp; pad rows masked in reduce
        const float* __restrict__ pi = img + (size_t)img_i * (NE * HW) + m;
        #pragma unroll
        for (int ks = 0; ks < 8; ++ks) {
            int kb = ks * 16 + h * 8;
            bf16x8 a;
            #pragma unroll
            for (int j = 0; j < 8; ++j)
                a[j] = (__bf16)pi[(kb + j) * HW];
            afrag[ks] = a;
        }
    }

    const float* __restrict__ tsrc0 = txt + (size_t)tb * NL * NL * NE;

    // ---- stage round 0 (texts 0,1) into buf[0] ----
    {
        #pragma unroll
        for (int r = 0; r < 4; ++r) {
            int ch = tid + 256 * r;          // 16B-chunk id 0..1023
            const float* p = tsrc0 + ch * 8;
            float4 f0 = *(const float4*)p;
            float4 f1 = *(const float4*)(p + 4);
            union { __bf16 b[8]; int4 v; } u;
            u.b[0] = (__bf16)f0.x; u.b[1] = (__bf16)f0.y;
            u.b[2] = (__bf16)f0.z; u.b[3] = (__bf16)f0.w;
            u.b[4] = (__bf16)f1.x; u.b[5] = (__bf16)f1.y;
            u.b[6] = (__bf16)f1.z; u.b[7] = (__bf16)f1.w;
            int row = ch >> 4;               // 0..63 = ts*32 + l
            int off = (row * 256 + (ch & 15) * 16) ^ ((row & 15) << 4);
            *(int4*)((char*)buf[0] + off) = u.v;
        }
    }
    __syncthreads();

    int c = 0;
    #pragma unroll 1
    for (int rnd = 0; rnd < 16; ++rnd) {
        // ---- stage next round into buf[c^1] (safe: barrier rnd-1 passed) ----
        if (rnd < 15) {
            const float* __restrict__ src = tsrc0 + (size_t)(rnd + 1) * 2 * NL * NE;
            #pragma unroll
            for (int r = 0; r < 4; ++r) {
                int ch = tid + 256 * r;
                const float* p = src + ch * 8;
                float4 f0 = *(const float4*)p;
                float4 f1 = *(const float4*)(p + 4);
                union { __bf16 b[8]; int4 v; } u;
                u.b[0] = (__bf16)f0.x; u.b[1] = (__bf16)f0.y;
                u.b[2] = (__bf16)f0.z; u.b[3] = (__bf16)f0.w;
                u.b[4] = (__bf16)f1.x; u.b[5] = (__bf16)f1.y;
                u.b[6] = (__bf16)f1.z; u.b[7] = (__bf16)f1.w;
                int row = ch >> 4;
                int off = (row * 256 + (ch & 15) * 16) ^ ((row & 15) << 4);
                *(int4*)((char*)buf[c ^ 1] + off) = u.v;
            }
        }

        // ---- compute 2 texts from buf[c] ----
        const __bf16* __restrict__ bsrc = buf[c];
        #pragma unroll
        for (int ts = 0; ts < 2; ++ts) {
            const int t = rnd * 2 + ts;          // text within chunk
            // B fragments: lane holds B[k = ks*16+h*8+j, n = ml]
            //            = txt[t, l=ml, e=k]   (same k-map as A)
            bf16x8 bfrag[8];
            {
                int row = ts * NL + ml;
                int sw  = (row & 15) << 4;
                #pragma unroll
                for (int ks = 0; ks < 8; ++ks) {
                    int off = (row * 256 + ks * 32 + h * 16) ^ sw;
                    bfrag[ks] = *(const bf16x8*)((const char*)bsrc + off);
                }
            }
            f32x16 acc = (f32x16)(0.f);
            #pragma unroll
            for (int ks = 0; ks < 8; ++ks)
                acc = __builtin_amdgcn_mfma_f32_32x32x16_bf16(
                    afrag[ks], bfrag[ks], acc, 0, 0, 0);

            // max over this wave's valid rows; C/D: col = lane&31,
            // row r2 = (reg&3)+8*(reg>>2)+4*h, m = mh*32+r2 (valid m<49)
            float cm;
            if (mh == 0) {                   // all 16 regs valid
                float t0[8];
                #pragma unroll
                for (int k = 0; k < 8; ++k) t0[k] = fmaxf(acc[2*k], acc[2*k+1]);
                float t1[4];
                #pragma unroll
                for (int k = 0; k < 4; ++k) t1[k] = fmaxf(t0[2*k], t0[2*k+1]);
                cm = fmaxf(fmaxf(t1[0], t1[1]), fmaxf(t1[2], t1[3]));
            } else {                         // regs 0..7 (+reg8 iff h==0)
                float u0[4];
                #pragma unroll
                for (int k = 0; k < 4; ++k) u0[k] = fmaxf(acc[2*k], acc[2*k+1]);
                cm = fmaxf(fmaxf(u0[0], u0[1]), fmaxf(u0[2], u0[3]));
                float ex = (h == 0) ? acc[8] : NEG_INF;
                cm = fmaxf(cm, ex);
            }
            atomicMax(&colmax[ii][t][ml], cm);   // ds_max, fire-and-forget
        }
        __syncthreads();
        c ^= 1;
    }

    // ---- batched epilogue: wave -> image (wave&1), texts of half (wave>>1) ----
    {
        const int iw  = wave & 1;
        const int th  = wave >> 1;
        const int t32 = th * 16 + (lane & 15);   // text within chunk
        const int q   = lane >> 4;               // col quarter 0..3
        const float* row = &colmax[iw][t32][q * 8];
        float4 a0 = *(const float4*)(row + 0);
        float4 a1 = *(const float4*)(row + 4);
        float s = ((a0.x + a0.y) + (a0.z + a0.w))
                + ((a1.x + a1.y) + (a1.z + a1.w));
        s += __shfl_xor(s, 16);
        s += __shfl_xor(s, 32);                  // sum over all 32 cols
        if (q == 0) {
            int tg = tb * NL + t32;
            float v = s * scale / (float)tlen[tg];
            out[img_i * NT + tg] = v;              // logits_per_image[i,t]
            out[NI * NT + tg * NI + img_i] = v;    // logits_per_text[t,i]
        }
    }
}

extern "C" void kernel_launch(void* const* d_in, const int* in_sizes, int n_in,
                              void* d_out, int out_size, void* d_ws, size_t ws_size,
                              hipStream_t stream)
{
    const float* img  = (const float*)d_in[0];
    const float* txt  = (const float*)d_in[1];
    const int*   tlen = (const int*)d_in[2];
    const float* nlt  = (const float*)d_in[3];
    float* out = (float*)d_out;
    clip_match_kernel<<<dim3(1024), dim3(256), 0, stream>>>(img, txt, tlen, nlt, out);
}

// Round 7
// 45.111 us; speedup vs baseline: 1.0796x; 1.0796x over previous
//
#include <hip/hip_runtime.h>

typedef __bf16 bf16x8 __attribute__((ext_vector_type(8)));
typedef float  f32x16 __attribute__((ext_vector_type(16)));

#define NI 256
#define NT 256
#define NL 32
#define NE 128
#define HW 49
#define NEG_INF (-3.0e38f)

// Block: 4 waves; wave w owns image ig*4+w COMPLETELY (M=64 pad of 49,
// 2 m-tiles -> 2 independent MFMA chains, 16 MFMA per 8 ds_read_b128).
// Grid: 512 = 64 image-groups x 8 text-chunks (32 texts) = 2 blocks/CU, no tail.
// LDS 80KB: 2 x 32KB round buffers (4 texts each, XOR-swizzled) + 16KB colmax.
// One barrier per round (8 rounds). T14 split pinned with sched_barrier(0):
// issue pf loads -> [fence] -> 64 MFMA -> [fence] -> cvt+ds_write -> barrier.
__global__ __launch_bounds__(256, 2)
void clip_match_kernel(const float* __restrict__ img,
                       const float* __restrict__ txt,
                       const int* __restrict__ tlen,
                       const float* __restrict__ nlt,
                       float* __restrict__ out)
{
    const int tid  = threadIdx.x;
    const int wave = tid >> 6, lane = tid & 63;
    const int ml   = lane & 31, h = lane >> 5;
    const int tb   = blockIdx.x & 7;     // text chunk (32 texts)
    const int ig   = blockIdx.x >> 3;    // image group (4 images)
    const int img_i = ig * 4 + wave;

    const float scale = expf(nlt[0]);

    __shared__ __align__(16) __bf16 buf[2][4 * NL * NE];   // 2 x 32 KB
    __shared__ __align__(16) float  colmax[4][NL][32];     // 16 KB, wave-private

    // ---- A fragments: full image, [64(pad 49) x 128] bf16, 64 VGPRs ----
    // lane holds A[m = mt*32+ml, k = ks*16 + h*8 + j]; A[m,k] = img[i,e=k,hw=m]
    bf16x8 afrag[2][8];
    {
        const float* __restrict__ pi = img + (size_t)img_i * (NE * HW);
        #pragma unroll
        for (int mt = 0; mt < 2; ++mt) {
            int m = mt * 32 + ml;
            if (m > HW - 1) m = HW - 1;      // clamp; pad rows masked in reduce
            #pragma unroll
            for (int ks = 0; ks < 8; ++ks) {
                int kb = ks * 16 + h * 8;
                bf16x8 a;
                #pragma unroll
                for (int j = 0; j < 8; ++j)
                    a[j] = (__bf16)pi[(kb + j) * HW + m];
                afrag[mt][ks] = a;
            }
        }
    }

    const float* __restrict__ tsrc0 = txt + (size_t)tb * NL * NL * NE;

    // ---- prologue: stage round 0 (texts 0..3) into buf[0] ----
    {
        #pragma unroll
        for (int q = 0; q < 8; ++q) {
            int ch = tid + 256 * q;          // 8-elem chunk id 0..2047
            const float* p = tsrc0 + ch * 8;
            float4 f0 = *(const float4*)p;
            float4 f1 = *(const float4*)(p + 4);
            union { __bf16 b[8]; int4 v; } u;
            u.b[0] = (__bf16)f0.x; u.b[1] = (__bf16)f0.y;
            u.b[2] = (__bf16)f0.z; u.b[3] = (__bf16)f0.w;
            u.b[4] = (__bf16)f1.x; u.b[5] = (__bf16)f1.y;
            u.b[6] = (__bf16)f1.z; u.b[7] = (__bf16)f1.w;
            int row = ch >> 4;               // 0..127 = ts*32 + l
            int off = (row * 256 + (ch & 15) * 16) ^ ((row & 15) << 4);
            *(int4*)((char*)buf[0] + off) = u.v;
        }
    }
    __syncthreads();

    int c = 0;
    #pragma unroll 1
    for (int rnd = 0; rnd < 8; ++rnd) {
        // ---- issue next round's global loads (stay in flight over compute) ----
        float4 pf[16];
        if (rnd < 7) {
            const float* __restrict__ src = tsrc0 + (size_t)(rnd + 1) * 4 * NL * NE;
            #pragma unroll
            for (int q = 0; q < 8; ++q) {
                const float* p = src + (tid + 256 * q) * 8;
                pf[2 * q]     = *(const float4*)p;
                pf[2 * q + 1] = *(const float4*)(p + 4);
            }
        }
        __builtin_amdgcn_sched_barrier(0);   // pin load issue before compute

        // ---- compute 4 texts from buf[c] ----
        const __bf16* __restrict__ bsrc = buf[c];
        #pragma unroll
        for (int ts = 0; ts < 4; ++ts) {
            const int t = rnd * 4 + ts;          // text within chunk
            // B frags: lane holds B[k = ks*16+h*8+j, n=ml] = txt[t,l=ml,e=k]
            bf16x8 bfrag[8];
            {
                int row = ts * NL + ml;
                int sw  = (row & 15) << 4;
                #pragma unroll
                for (int ks = 0; ks < 8; ++ks) {
                    int off = (row * 256 + ks * 32 + h * 16) ^ sw;
                    bfrag[ks] = *(const bf16x8*)((const char*)bsrc + off);
                }
            }
            f32x16 acc0 = (f32x16)(0.f);
            f32x16 acc1 = (f32x16)(0.f);
            #pragma unroll
            for (int ks = 0; ks < 8; ++ks) {     // 2 independent chains
                acc0 = __builtin_amdgcn_mfma_f32_32x32x16_bf16(
                    afrag[0][ks], bfrag[ks], acc0, 0, 0, 0);
                acc1 = __builtin_amdgcn_mfma_f32_32x32x16_bf16(
                    afrag[1][ks], bfrag[ks], acc1, 0, 0, 0);
            }
            // max over rows; C/D: col = lane&31, row r2 = (reg&3)+8*(reg>>2)+4*h
            // acc0: m = r2 (all 16 valid); acc1: m = 32+r2, regs 0..7 + reg8@h==0
            float t0[8];
            #pragma unroll
            for (int k = 0; k < 8; ++k) t0[k] = fmaxf(acc0[2*k], acc0[2*k+1]);
            float t1[4];
            #pragma unroll
            for (int k = 0; k < 4; ++k) t1[k] = fmaxf(t0[2*k], t0[2*k+1]);
            float a0m = fmaxf(fmaxf(t1[0], t1[1]), fmaxf(t1[2], t1[3]));
            float u0[4];
            #pragma unroll
            for (int k = 0; k < 4; ++k) u0[k] = fmaxf(acc1[2*k], acc1[2*k+1]);
            float a1m = fmaxf(fmaxf(u0[0], u0[1]), fmaxf(u0[2], u0[3]));
            float ex  = (h == 0) ? acc1[8] : NEG_INF;
            float cm  = fmaxf(fmaxf(a0m, a1m), ex);
            cm = fmaxf(cm, __shfl_xor(cm, 32));     // merge h-halves: full col max
            if (h == 0) colmax[wave][t][ml] = cm;   // plain store, wave-private
        }
        __builtin_amdgcn_sched_barrier(0);   // keep cvt/ds_write after compute

        // ---- write-half of staging into buf[c^1] ----
        if (rnd < 7) {
            __bf16* __restrict__ dst = buf[c ^ 1];
            #pragma unroll
            for (int q = 0; q < 8; ++q) {
                int ch = tid + 256 * q;
                float4 f0 = pf[2 * q];
                float4 f1 = pf[2 * q + 1];
                union { __bf16 b[8]; int4 v; } u;
                u.b[0] = (__bf16)f0.x; u.b[1] = (__bf16)f0.y;
                u.b[2] = (__bf16)f0.z; u.b[3] = (__bf16)f0.w;
                u.b[4] = (__bf16)f1.x; u.b[5] = (__bf16)f1.y;
                u.b[6] = (__bf16)f1.z; u.b[7] = (__bf16)f1.w;
                int row = ch >> 4;
                int off = (row * 256 + (ch & 15) * 16) ^ ((row & 15) << 4);
                *(int4*)((char*)dst + off) = u.v;
            }
        }
        __syncthreads();
        c ^= 1;
    }

    // ---- batched epilogue: wave reads its own colmax [32 texts][32 cols] ----
    {
        const int t = ml;                        // text within chunk
        const float* row = &colmax[wave][t][h * 16];
        float4 a0 = *(const float4*)(row + 0);
        float4 a1 = *(const float4*)(row + 4);
        float4 a2 = *(const float4*)(row + 8);
        float4 a3 = *(const float4*)(row + 12);
        float s = ((a0.x + a0.y) + (a0.z + a0.w))
                + ((a1.x + a1.y) + (a1.z + a1.w))
                + ((a2.x + a2.y) + (a2.z + a2.w))
                + ((a3.x + a3.y) + (a3.z + a3.w));
        s += __shfl_xor(s, 32);                  // both 16-col halves
        if (h == 0) {
            int tg = tb * NL + t;
            float v = s * scale / (float)tlen[tg];
            out[img_i * NT + tg] = v;              // logits_per_image[i,t]
            out[NI * NT + tg * NI + img_i] = v;    // logits_per_text[t,i]
        }
    }
}

extern "C" void kernel_launch(void* const* d_in, const int* in_sizes, int n_in,
                              void* d_out, int out_size, void* d_ws, size_t ws_size,
                              hipStream_t stream)
{
    const float* img  = (const float*)d_in[0];
    const float* txt  = (const float*)d_in[1];
    const int*   tlen = (const int*)d_in[2];
    const float* nlt  = (const float*)d_in[3];
    float* out = (float*)d_out;
    clip_match_kernel<<<dim3(512), dim3(256), 0, stream>>>(img, txt, tlen, nlt, out);
}

// Round 8
// 43.640 us; speedup vs baseline: 1.1160x; 1.0337x over previous
//
#include <hip/hip_runtime.h>

typedef __bf16 bf16x8 __attribute__((ext_vector_type(8)));
typedef float  f32x16 __attribute__((ext_vector_type(16)));

#define NI 256
#define NT 256
#define NL 32
#define NE 128
#define HW 49
#define NEG_INF (-3.0e38f)

// ws layout (bf16), validated in R5:
//  wsA: frag gw = (i*2+mt)*8+ks, elem (gw*64+lane)*8+j
//       = img[i, e=ks*16+(lane>>5)*8+j, hw=min(mt*32+(lane&31),48)]   (4 MB)
//  wsB: frag gw = t*8+ks, elem (gw*64+lane)*8+j
//       = txt[t, l=lane&31, e=ks*16+(lane>>5)*8+j]                    (2 MB)

// ---------- pre-kernel: fp32 -> bf16 MFMA-fragment layout ----------
__global__ __launch_bounds__(256, 4)
void prep_kernel(const float* __restrict__ img,
                 const float* __restrict__ txt,
                 __bf16* __restrict__ wsA,
                 __bf16* __restrict__ wsB)
{
    const int tid  = threadIdx.x;
    const int wave = tid >> 6, lane = tid & 63;
    const int ml   = lane & 31, h = lane >> 5;
    const int bid  = blockIdx.x;
    if (bid < 1024) {                       // A-part: 4096 waves
        int gw = bid * 4 + wave;            // (i, mt, ks)
        int i  = gw >> 4, mt = (gw >> 3) & 1, ks = gw & 7;
        int m  = mt * 32 + ml; if (m > HW - 1) m = HW - 1;
        int e0 = ks * 16 + h * 8;
        const float* p = img + ((size_t)i * NE + e0) * HW + m;
        union { __bf16 b[8]; int4 v; } u;
        #pragma unroll
        for (int j = 0; j < 8; ++j) u.b[j] = (__bf16)p[j * HW];
        *(int4*)(wsA + ((size_t)gw * 64 + lane) * 8) = u.v;
    } else {                                // B-part: 2048 waves
        int gw = (bid - 1024) * 4 + wave;   // (t, ks)
        int t  = gw >> 3, ks = gw & 7;
        int e0 = ks * 16 + h * 8;
        const float* p = txt + ((size_t)t * NL + ml) * NE + e0;
        float4 f0 = *(const float4*)p;
        float4 f1 = *(const float4*)(p + 4);
        union { __bf16 b[8]; int4 v; } u;
        u.b[0] = (__bf16)f0.x; u.b[1] = (__bf16)f0.y;
        u.b[2] = (__bf16)f0.z; u.b[3] = (__bf16)f0.w;
        u.b[4] = (__bf16)f1.x; u.b[5] = (__bf16)f1.y;
        u.b[6] = (__bf16)f1.z; u.b[7] = (__bf16)f1.w;
        *(int4*)(wsB + ((size_t)gw * 64 + lane) * 8) = u.v;
    }
}

// stage one round (4 texts = 32 KB) via global_load_lds: 8 x 1KB per wave
__device__ inline void stage_round(const __bf16* __restrict__ gsrc,
                                   __bf16* dst, int wave, int lane)
{
    #pragma unroll
    for (int q = 0; q < 8; ++q) {
        int seg = wave * 8 + q;             // 32 segments of 512 elems
        const __bf16* g = gsrc + (size_t)seg * 512 + lane * 8;
        __bf16*       l = dst  + (size_t)seg * 512 + lane * 8;
        __builtin_amdgcn_global_load_lds(
            (const __attribute__((address_space(1))) void*)g,
            (__attribute__((address_space(3)))       void*)l, 16, 0, 0);
    }
}

// ---------- main kernel ----------
// Block: 4 waves; wave w owns TWO images (M=128): 8 ds_read_b128 -> 32 MFMA
// per text (F=4). Block = 8 images x 16-text chunk. Grid 512 = 32 img-groups
// x 16 chunks = 2 blocks/CU, zero tail. LDS 80KB: 2x32KB dbuf + 16KB colmax.
// 4 rounds, one barrier each; staging = global_load_lds (no VALU, no VGPR).
__global__ __launch_bounds__(256, 2)
void clip_match_kernel(const __bf16* __restrict__ wsA,
                       const __bf16* __restrict__ wsB,
                       const int* __restrict__ tlen,
                       const float* __restrict__ nlt,
                       float* __restrict__ out)
{
    const int tid  = threadIdx.x;
    const int wave = tid >> 6, lane = tid & 63;
    const int ml   = lane & 31, h = lane >> 5;
    const int tb   = blockIdx.x & 15;    // text chunk (16 texts)
    const int ig   = blockIdx.x >> 4;    // image group (8 images)

    const float scale = expf(nlt[0]);

    __shared__ __align__(16) __bf16 buf[2][4 * NL * NE];   // 2 x 32 KB (4 texts)
    __shared__ __align__(16) float  colmax[8][16][32];     // 16 KB, wave-private

    // ---- A fragments: 2 images, fragment-linear, 32 coalesced dwordx4 ----
    bf16x8 afrag[2][2][8];               // [img][mt][ks], 128 VGPRs
    {
        #pragma unroll
        for (int p = 0; p < 2; ++p) {
            int im = ig * 8 + wave * 2 + p;
            const __bf16* pa = wsA + (size_t)im * 2 * 8 * 512;
            #pragma unroll
            for (int mt = 0; mt < 2; ++mt)
                #pragma unroll
                for (int ks = 0; ks < 8; ++ks)
                    afrag[p][mt][ks] = *(const bf16x8*)(
                        pa + (size_t)((mt * 8 + ks) * 64 + lane) * 8);
        }
    }

    const __bf16* csrc = wsB + (size_t)tb * 16 * 8 * 512;  // chunk base

    stage_round(csrc, buf[0], wave, lane);                 // texts 0..3
    __syncthreads();

    int c = 0;
    #pragma unroll 1
    for (int rnd = 0; rnd < 4; ++rnd) {
        if (rnd < 3)
            stage_round(csrc + (size_t)(rnd + 1) * 4 * 4096, buf[c ^ 1],
                        wave, lane);

        const __bf16* __restrict__ bsrc = buf[c];
        #pragma unroll
        for (int ts = 0; ts < 4; ++ts) {
            const int t = rnd * 4 + ts;          // text within chunk
            f32x16 acc[2][2];                    // [img][mt]
            #pragma unroll
            for (int p = 0; p < 2; ++p)
                #pragma unroll
                for (int mt = 0; mt < 2; ++mt)
                    acc[p][mt] = (f32x16)(0.f);
            #pragma unroll
            for (int ks = 0; ks < 8; ++ks) {
                bf16x8 bfrag = *(const bf16x8*)(
                    bsrc + (size_t)ts * 4096 + (size_t)(ks * 64 + lane) * 8);
                acc[0][0] = __builtin_amdgcn_mfma_f32_32x32x16_bf16(
                    afrag[0][0][ks], bfrag, acc[0][0], 0, 0, 0);
                acc[0][1] = __builtin_amdgcn_mfma_f32_32x32x16_bf16(
                    afrag[0][1][ks], bfrag, acc[0][1], 0, 0, 0);
                acc[1][0] = __builtin_amdgcn_mfma_f32_32x32x16_bf16(
                    afrag[1][0][ks], bfrag, acc[1][0], 0, 0, 0);
                acc[1][1] = __builtin_amdgcn_mfma_f32_32x32x16_bf16(
                    afrag[1][1][ks], bfrag, acc[1][1], 0, 0, 0);
            }
            // per image: max over valid rows. C/D: col = lane&31,
            // row r2 = (reg&3)+8*(reg>>2)+4*h; mt0: m=r2 all valid;
            // mt1: m=32+r2 -> regs 0..7 valid, reg8 valid iff h==0 (m=48).
            #pragma unroll
            for (int p = 0; p < 2; ++p) {
                float t0[8];
                #pragma unroll
                for (int k = 0; k < 8; ++k)
                    t0[k] = fmaxf(acc[p][0][2*k], acc[p][0][2*k+1]);
                float t1[4];
                #pragma unroll
                for (int k = 0; k < 4; ++k)
                    t1[k] = fmaxf(t0[2*k], t0[2*k+1]);
                float a0m = fmaxf(fmaxf(t1[0], t1[1]), fmaxf(t1[2], t1[3]));
                float u0[4];
                #pragma unroll
                for (int k = 0; k < 4; ++k)
                    u0[k] = fmaxf(acc[p][1][2*k], acc[p][1][2*k+1]);
                float a1m = fmaxf(fmaxf(u0[0], u0[1]), fmaxf(u0[2], u0[3]));
                float ex  = (h == 0) ? acc[p][1][8] : NEG_INF;
                float cm  = fmaxf(fmaxf(a0m, a1m), ex);
                cm = fmaxf(cm, __shfl_xor(cm, 32));   // merge h-halves
                if (h == 0) colmax[wave * 2 + p][t][ml] = cm;
            }
        }
        __syncthreads();
        c ^= 1;
    }

    // ---- epilogue (no barrier needed: colmax is wave-private) ----
    {
        const int t = ml & 15;               // text within chunk
        const int p = ml >> 4;               // which of this wave's 2 images
        const float* row = &colmax[wave * 2 + p][t][h * 16];
        float4 a0 = *(const float4*)(row + 0);
        float4 a1 = *(const float4*)(row + 4);
        float4 a2 = *(const float4*)(row + 8);
        float4 a3 = *(const float4*)(row + 12);
        float s = ((a0.x + a0.y) + (a0.z + a0.w))
                + ((a1.x + a1.y) + (a1.z + a1.w))
                + ((a2.x + a2.y) + (a2.z + a2.w))
                + ((a3.x + a3.y) + (a3.z + a3.w));
        s += __shfl_xor(s, 32);              // both 16-col halves
        if (h == 0) {
            int tg = tb * 16 + t;
            int im = ig * 8 + wave * 2 + p;
            float v = s * scale / (float)tlen[tg];
            out[im * NT + tg] = v;              // logits_per_image[i,t]
            out[NI * NT + tg * NI + im] = v;    // logits_per_text[t,i]
        }
    }
}

extern "C" void kernel_launch(void* const* d_in, const int* in_sizes, int n_in,
                              void* d_out, int out_size, void* d_ws, size_t ws_size,
                              hipStream_t stream)
{
    const float* img  = (const float*)d_in[0];
    const float* txt  = (const float*)d_in[1];
    const int*   tlen = (const int*)d_in[2];
    const float* nlt  = (const float*)d_in[3];
    float* out = (float*)d_out;

    __bf16* wsA = (__bf16*)d_ws;                 // 4 MB
    __bf16* wsB = wsA + (size_t)4096 * 512;      // 2 MB

    prep_kernel<<<dim3(1536), dim3(256), 0, stream>>>(img, txt, wsA, wsB);
    clip_match_kernel<<<dim3(512), dim3(256), 0, stream>>>(wsA, wsB, tlen, nlt, out);
}